// Round 3
// baseline (1051.268 us; speedup 1.0000x reference)
//
#include <hip/hip_runtime.h>
#include <math.h>

#define NPROP 512
#define NB 2
#define NROWS (NB*NPROP)          // 1024
#define FCH 256
#define FH 64
#define FW 64
#define INDIM (FCH*7*7)           // 12544
#define HID 1024
#define NCLS 81
#define CAND_PER_IMG (NPROP*(NCLS-1))  // 40960
#define CLIPV 4.1351666f          // log(1000/16) rounded to f32

typedef _Float16 f16x8 __attribute__((ext_vector_type(8)));
typedef float f32x4 __attribute__((ext_vector_type(4)));
typedef unsigned int u32;

__device__ __forceinline__ void gload16(const void* g, void* l) {
    __builtin_amdgcn_global_load_lds((const __attribute__((address_space(1))) u32*)g,
                                     (__attribute__((address_space(3))) u32*)l, 16, 0, 0);
}

// ---- workspace layout (bytes) ----
#define XHI_OFF    0ull
#define XLO_OFF    25690112ull
#define WT1HI_OFF  51380224ull
#define WT1LO_OFF  77070336ull
#define WT2HI_OFF  102760448ull
#define WT2LO_OFF  104857600ull
#define H1HI_OFF   106954752ull
#define H1LO_OFF   109051904ull
#define H2_OFF     111149056ull
#define CWT_OFF    115343360ull
#define BWT_OFF    116338688ull
#define PROBS_OFF  116387840ull
#define CUR_OFF    116719616ull
#define CNT_OFF    116736000ull
#define CS_OFF     116736256ull
#define CBX_OFF    117063936ull
#define COB_OFF    118374656ull
#define CAR_OFF    119685376ull
#define CLB_OFF    120013056ull
#define CIX_OFF    120340736ull
#define PART_OFF   120668416ull
// PART: up to 14 planes of 1024x1024 fp32 = 58.7 MB -> total ~179 MB

__global__ void init_kernel(int* cnt) {
    if (threadIdx.x < 2) cnt[threadIdx.x] = 0;
}

// one block per (b,n) proposal; writes scaled f16 limb planes of X
__global__ __launch_bounds__(256) void roi_align_kernel(
    const float* __restrict__ feat, const float* __restrict__ boxes,
    _Float16* __restrict__ Xhi, _Float16* __restrict__ Xlo)
{
    int r = blockIdx.x;           // b*512+n
    int b = r >> 9;
    const float* f = feat + (size_t)b * (FCH*FH*FW);
    __shared__ float sb[4];
    __shared__ int   sx0[49], sx1[49], sy0[49], sy1[49];
    __shared__ float sw00[49], sw01[49], sw10[49], sw11[49];
    int tid = threadIdx.x;
    if (tid == 0) {
        float x1 = boxes[r*4+0]*0.125f, y1 = boxes[r*4+1]*0.125f;
        float x2 = boxes[r*4+2]*0.125f, y2 = boxes[r*4+3]*0.125f;
        sb[0] = x1; sb[1] = y1;
        sb[2] = fmaxf(x2-x1, 1.0f) / 7.0f;   // bw
        sb[3] = fmaxf(y2-y1, 1.0f) / 7.0f;   // bh
    }
    __syncthreads();
    if (tid < 49) {
        int py = tid / 7, px = tid - py*7;
        float gx = sb[0] + ((float)px + 0.5f)*sb[2];
        float gy = sb[1] + ((float)py + 0.5f)*sb[3];
        gx = fminf(fmaxf(gx, 0.0f), 63.0f);
        gy = fminf(fmaxf(gy, 0.0f), 63.0f);
        float x0f = floorf(gx), y0f = floorf(gy);
        int x0 = (int)x0f, y0 = (int)y0f;
        sx0[tid] = x0; sy0[tid] = y0;
        sx1[tid] = min(x0+1, 63); sy1[tid] = min(y0+1, 63);
        float dx = gx - x0f, dy = gy - y0f;
        sw00[tid] = (1.0f-dy)*(1.0f-dx);
        sw01[tid] = (1.0f-dy)*dx;
        sw10[tid] = dy*(1.0f-dx);
        sw11[tid] = dy*dx;
    }
    __syncthreads();
    size_t xbase = (size_t)r * INDIM;
    for (int i = tid; i < INDIM; i += 256) {
        int c = i / 49;
        int p = i - c*49;
        const float* fc = f + c*(FH*FW);
        int r0 = sy0[p]*FW, r1 = sy1[p]*FW;
        float v = fc[r0 + sx0[p]]*sw00[p] + fc[r0 + sx1[p]]*sw01[p]
                + fc[r1 + sx0[p]]*sw10[p] + fc[r1 + sx1[p]]*sw11[p];
        float vs = v * 32.0f;
        _Float16 h = (_Float16)vs;
        Xhi[xbase + i] = h;
        Xlo[xbase + i] = (_Float16)(vs - (float)h);
    }
}

// in [K][N] fp32 -> hi/lo [N][K] f16 (scaled). K,N multiples of 32.
__global__ __launch_bounds__(256) void trans_limb(
    const float* __restrict__ in, _Float16* __restrict__ hi, _Float16* __restrict__ lo,
    int K, int N, float scale)
{
    __shared__ float t[32][33];
    int tx = threadIdx.x & 31, ty = threadIdx.x >> 5;   // ty 0..7
    int n0 = blockIdx.x << 5, k0 = blockIdx.y << 5;
#pragma unroll
    for (int r = 0; r < 4; ++r)
        t[ty + 8*r][tx] = in[(size_t)(k0 + ty + 8*r)*N + n0 + tx];
    __syncthreads();
#pragma unroll
    for (int r = 0; r < 4; ++r) {
        int n = n0 + ty + 8*r, k = k0 + tx;
        float v = t[tx][ty + 8*r] * scale;
        _Float16 h = (_Float16)v;
        hi[(size_t)n*K + k] = h;
        lo[(size_t)n*K + k] = (_Float16)(v - (float)h);
    }
}

// batched plain transpose: in [b][K][N] -> out [b][N][K] (fp32, small)
__global__ __launch_bounds__(256) void trans_naive(
    const float* __restrict__ in, float* __restrict__ out, int K, int N, int batch)
{
    int idx = blockIdx.x*256 + threadIdx.x;
    int per = K*N;
    if (idx >= per*batch) return;
    int b = idx / per;
    int rem = idx - b*per;
    int n = rem / K, k = rem - n*K;
    out[idx] = in[(size_t)b*per + (size_t)k*N + n];
}

// ---------------------------------------------------------------------------
// Pure-f16-limb MFMA split-K GEMM with global_load_lds staging.
// A hi/lo [M][K] f16 (x32), B hi/lo [N][K] f16 transposed (x64).
// 128x128 tile, 256 thr = 4 waves (2x2), 4x4 frags of 16x16x32, 3 limb products.
// partial fp32 [z][1024][1024]; unscale 1/2048 in reduce.
// ---------------------------------------------------------------------------
__global__ __launch_bounds__(256) void mfma_gemm_limb(
    const _Float16* __restrict__ Ahi, const _Float16* __restrict__ Alo,
    const _Float16* __restrict__ Bhi, const _Float16* __restrict__ Blo,
    float* __restrict__ part, int K, int ksteps)
{
    // plane p: 0=Ahi 1=Alo 2=Bhi 3=Blo; slot = ks*128 + row, 16B per slot
    __shared__ __align__(16) _Float16 lds[4][512][8];
    const int tid = threadIdx.x;
    const int lane = tid & 63;
    const int w = tid >> 6, wm = w >> 1, wn = w & 1;
    const int kg = lane >> 4, lr = lane & 15;
    const int row0 = blockIdx.y << 7, col0 = blockIdx.x << 7;
    const int kb0 = blockIdx.z * ksteps * 32;
    const int r_ = tid & 127;
    const int ks1 = tid >> 7;          // 0 or 1
    const int wb = tid & 192;          // wave-uniform slot base

    const _Float16* srcA0 = Ahi + (size_t)(row0 + r_) * K + ks1*8;
    const _Float16* srcA1 = Alo + (size_t)(row0 + r_) * K + ks1*8;
    const _Float16* srcB0 = Bhi + (size_t)(col0 + r_) * K + ks1*8;
    const _Float16* srcB1 = Blo + (size_t)(col0 + r_) * K + ks1*8;

    f32x4 acc[4][4];
#pragma unroll
    for (int i = 0; i < 4; ++i)
#pragma unroll
        for (int j = 0; j < 4; ++j) acc[i][j] = (f32x4){0.f, 0.f, 0.f, 0.f};

#define STAGE(kb) do { \
    gload16(srcA0 + (kb),      (void*)&lds[0][wb][0]); \
    gload16(srcA0 + (kb) + 16, (void*)&lds[0][256 + wb][0]); \
    gload16(srcA1 + (kb),      (void*)&lds[1][wb][0]); \
    gload16(srcA1 + (kb) + 16, (void*)&lds[1][256 + wb][0]); \
    gload16(srcB0 + (kb),      (void*)&lds[2][wb][0]); \
    gload16(srcB0 + (kb) + 16, (void*)&lds[2][256 + wb][0]); \
    gload16(srcB1 + (kb),      (void*)&lds[3][wb][0]); \
    gload16(srcB1 + (kb) + 16, (void*)&lds[3][256 + wb][0]); \
} while (0)

    STAGE(kb0);
    for (int t = 0; t < ksteps; ++t) {
        __syncthreads();               // vmcnt drained: tile t resident
        f16x8 Ah[4], Al[4], Bh[4], Bl[4];
#pragma unroll
        for (int mi = 0; mi < 4; ++mi) {
            int s = kg*128 + wm*64 + mi*16 + lr;
            Ah[mi] = *(const f16x8*)&lds[0][s][0];
            Al[mi] = *(const f16x8*)&lds[1][s][0];
        }
#pragma unroll
        for (int ni = 0; ni < 4; ++ni) {
            int s = kg*128 + wn*64 + ni*16 + lr;
            Bh[ni] = *(const f16x8*)&lds[2][s][0];
            Bl[ni] = *(const f16x8*)&lds[3][s][0];
        }
        __syncthreads();               // all waves' frag reads complete
        if (t + 1 < ksteps) STAGE(kb0 + (t+1)*32);   // overlaps MFMA below
#pragma unroll
        for (int mi = 0; mi < 4; ++mi)
#pragma unroll
            for (int ni = 0; ni < 4; ++ni) {
                acc[mi][ni] = __builtin_amdgcn_mfma_f32_16x16x32_f16(Ah[mi], Bh[ni], acc[mi][ni], 0, 0, 0);
                acc[mi][ni] = __builtin_amdgcn_mfma_f32_16x16x32_f16(Ah[mi], Bl[ni], acc[mi][ni], 0, 0, 0);
                acc[mi][ni] = __builtin_amdgcn_mfma_f32_16x16x32_f16(Al[mi], Bh[ni], acc[mi][ni], 0, 0, 0);
            }
    }
#undef STAGE

    // epilogue: C/D layout col=lane&15, row=(lane>>4)*4+j  (verified r2)
    float* base = part + ((size_t)blockIdx.z << 20)
                + (size_t)row0*HID + col0 + wn*64 + lr;
#pragma unroll
    for (int mi = 0; mi < 4; ++mi) {
#pragma unroll
        for (int j = 0; j < 4; ++j) {
            int row = wm*64 + mi*16 + kg*4 + j;
            float* pr = base + (size_t)row*HID;
            pr[0]  = acc[mi][0][j];
            pr[16] = acc[mi][1][j];
            pr[32] = acc[mi][2][j];
            pr[48] = acc[mi][3][j];
        }
    }
}

// out = relu(sum_p part[p]/2048 + bias); mode 0: fp32 out; mode 1: f16 limb out (x32)
__global__ __launch_bounds__(256) void reduce_bias_relu(
    const float* __restrict__ part, const float* __restrict__ bias,
    float* __restrict__ out32, _Float16* __restrict__ outhi, _Float16* __restrict__ outlo,
    int nsplit, int mode)
{
    int gid = blockIdx.x*256 + threadIdx.x;
    float s = 0.f;
    for (int p = 0; p < nsplit; ++p) s += part[((size_t)p << 20) + gid];
    s = s * (1.0f/2048.0f) + bias[gid & (HID-1)];
    s = fmaxf(s, 0.f);
    if (mode == 0) {
        out32[gid] = s;
    } else {
        float vs = s * 32.0f;
        _Float16 h = (_Float16)vs;
        outhi[gid] = h;
        outlo[gid] = (_Float16)(vs - (float)h);
    }
}

// cls+bbox heads + decode (+softmax at last stage). 4 rows per block.
// cwT [81][1024], bwT [4][1024] transposed weights (per stage).
__global__ __launch_bounds__(512) void heads_kernel(
    const float* __restrict__ X, const float* __restrict__ cwT, const float* __restrict__ cb,
    const float* __restrict__ bwT, const float* __restrict__ bbb,
    float* __restrict__ cur, float* __restrict__ probs,
    const int* __restrict__ img_sz, int stage, int write_probs)
{
    __shared__ float xs[4][1024];
    __shared__ float lg[4][96];
    int tid = threadIdx.x;
    int lr = tid >> 7;           // local row 0..3
    int j  = tid & 127;
    int row0 = blockIdx.x * 4;
    for (int i = tid; i < 4096; i += 512)
        xs[i >> 10][i & 1023] = X[(size_t)(row0 + (i >> 10))*1024 + (i & 1023)];
    __syncthreads();
    int row = row0 + lr;
    if (j < 85) {
        const float* wrow = (j < 81) ? (cwT + (size_t)j*HID) : (bwT + (size_t)(j-81)*HID);
        float acc = (j < 81) ? cb[j] : bbb[j-81];
        const float4* w4 = (const float4*)wrow;
#pragma unroll 4
        for (int k4 = 0; k4 < 256; ++k4) {
            float4 wv = w4[k4];
            const float* xr = &xs[lr][k4*4];
            acc = fmaf(xr[0], wv.x, acc);
            acc = fmaf(xr[1], wv.y, acc);
            acc = fmaf(xr[2], wv.z, acc);
            acc = fmaf(xr[3], wv.w, acc);
        }
        lg[lr][j] = acc;
    }
    __syncthreads();
    if (j == 0) {   // box decode + clip
        float img = (float)(*img_sz);
        float px1 = cur[row*4+0], py1 = cur[row*4+1];
        float px2 = cur[row*4+2], py2 = cur[row*4+3];
        float pw = fmaxf(px2-px1, 1e-6f), ph = fmaxf(py2-py1, 1e-6f);
        float pcx = px1 + 0.5f*pw, pcy = py1 + 0.5f*ph;
        float wx, wy, ww, wh;
        if (stage == 0)      { wx=0.1f;   wy=0.1f;   ww=0.2f;   wh=0.2f;   }
        else if (stage == 1) { wx=0.05f;  wy=0.05f;  ww=0.1f;   wh=0.1f;   }
        else                 { wx=0.033f; wy=0.033f; ww=0.067f; wh=0.067f; }
        float dx = lg[lr][81]*wx, dy = lg[lr][82]*wy;
        float dw = fminf(lg[lr][83]*ww, CLIPV);
        float dh = fminf(lg[lr][84]*wh, CLIPV);
        float cx = dx*pw + pcx, cy = dy*ph + pcy;
        float w = expf(dw)*pw, h = expf(dh)*ph;
        cur[row*4+0] = fminf(fmaxf(cx - 0.5f*w, 0.f), img);
        cur[row*4+1] = fminf(fmaxf(cy - 0.5f*h, 0.f), img);
        cur[row*4+2] = fminf(fmaxf(cx + 0.5f*w, 0.f), img);
        cur[row*4+3] = fminf(fmaxf(cy + 0.5f*h, 0.f), img);
    }
    if (write_probs) {
        if (j == 1) {
            float m = lg[lr][0];
            for (int c2 = 1; c2 < 81; ++c2) m = fmaxf(m, lg[lr][c2]);
            float s = 0.f;
            for (int c2 = 0; c2 < 81; ++c2) s += expf(lg[lr][c2] - m);
            lg[lr][88] = m; lg[lr][89] = s;
        }
        __syncthreads();
        if (j < 81)
            probs[(size_t)row*81 + j] = expf(lg[lr][j] - lg[lr][88]) / lg[lr][89];
    }
}

__global__ __launch_bounds__(256) void compact_kernel(
    const float* __restrict__ probs, const float* __restrict__ cur,
    const int* __restrict__ img_sz, int* __restrict__ cnt,
    float* __restrict__ cscore, float4* __restrict__ cbox, float4* __restrict__ cob,
    float* __restrict__ carea, int* __restrict__ clabel, int* __restrict__ coidx)
{
    int gid = blockIdx.x*256 + threadIdx.x;
    if (gid >= NB*CAND_PER_IMG) return;
    int b = gid / CAND_PER_IMG;
    int rem = gid - b*CAND_PER_IMG;
    int n = rem / 80;
    int cm = rem - n*80;
    int label = cm + 1;
    int r = b*NPROP + n;
    float s = probs[(size_t)r*81 + label];
    float b0 = cur[r*4+0], b1 = cur[r*4+1], b2 = cur[r*4+2], b3 = cur[r*4+3];
    if (s > 0.05f && (b2 - b0) >= 1.0f && (b3 - b1) >= 1.0f) {
        int pos = atomicAdd(&cnt[b], 1);
        int base = b*CAND_PER_IMG + pos;
        float img = (float)(*img_sz);
        float t = (float)label * (img + 2.0f);
        float o0 = b0+t, o1 = b1+t, o2 = b2+t, o3 = b3+t;
        cscore[base] = s;
        cbox[base] = make_float4(b0, b1, b2, b3);
        cob[base]  = make_float4(o0, o1, o2, o3);
        carea[base] = fmaxf(o2-o0, 0.f) * fmaxf(o3-o1, 0.f);
        clabel[base] = label;
        coidx[base] = n*80 + cm;   // reference flat order for argmax tie-break
    }
}

__global__ __launch_bounds__(256) void nms_kernel(
    const int* __restrict__ cnt, float* __restrict__ cscore,
    const float4* __restrict__ cbox, const float4* __restrict__ cob,
    const float* __restrict__ carea, const int* __restrict__ clabel,
    const int* __restrict__ coidx, float* __restrict__ out)
{
    int b = blockIdx.x;
    int tid = threadIdx.x;
    int M = cnt[b];
    int base0 = b*CAND_PER_IMG;
    __shared__ float rs[256]; __shared__ int ri[256]; __shared__ int rp[256];
    __shared__ float sel[5];
    for (int it = 0; it < 100; ++it) {
        float best = -1e30f; int bo = 0x7fffffff; int bp = -1;
        for (int jj = tid; jj < M; jj += 256) {
            float s = cscore[base0+jj];
            int oi = coidx[base0+jj];
            if (s > best || (s == best && oi < bo)) { best = s; bo = oi; bp = jj; }
        }
        rs[tid] = best; ri[tid] = bo; rp[tid] = bp;
        __syncthreads();
        for (int off = 128; off > 0; off >>= 1) {
            if (tid < off) {
                if (rs[tid+off] > rs[tid] ||
                    (rs[tid+off] == rs[tid] && ri[tid+off] < ri[tid])) {
                    rs[tid] = rs[tid+off]; ri[tid] = ri[tid+off]; rp[tid] = rp[tid+off];
                }
            }
            __syncthreads();
        }
        float ssel = rs[0]; int pos = rp[0];
        if (ssel > 0.0f) {
            if (tid == 0) {
                float4 bx = cbox[base0+pos];
                out[b*400 + it*4 + 0] = bx.x;
                out[b*400 + it*4 + 1] = bx.y;
                out[b*400 + it*4 + 2] = bx.z;
                out[b*400 + it*4 + 3] = bx.w;
                out[800  + b*100 + it] = ssel;
                out[1000 + b*100 + it] = (float)clabel[base0+pos];
                float4 ob = cob[base0+pos];
                sel[0] = ob.x; sel[1] = ob.y; sel[2] = ob.z; sel[3] = ob.w;
                sel[4] = carea[base0+pos];
                cscore[base0+pos] = -1.0f;
            }
            __syncthreads();
            float bi0 = sel[0], bi1 = sel[1], bi2 = sel[2], bi3 = sel[3], ai = sel[4];
            for (int jj = tid; jj < M; jj += 256) {
                float4 ob = cob[base0+jj];
                float ix1 = fmaxf(bi0, ob.x), iy1 = fmaxf(bi1, ob.y);
                float ix2 = fminf(bi2, ob.z), iy2 = fminf(bi3, ob.w);
                float inter = fmaxf(ix2-ix1, 0.f) * fmaxf(iy2-iy1, 0.f);
                float iou = inter / (ai + carea[base0+jj] - inter + 1e-9f);
                if (iou > 0.5f) cscore[base0+jj] = -1.0f;
            }
        } else {
            if (tid == 0) {
                out[b*400+it*4+0] = 0.f; out[b*400+it*4+1] = 0.f;
                out[b*400+it*4+2] = 0.f; out[b*400+it*4+3] = 0.f;
                out[800 + b*100 + it] = 0.f;
                out[1000 + b*100 + it] = 0.f;
            }
        }
        __syncthreads();
    }
}

extern "C" void kernel_launch(void* const* d_in, const int* in_sizes, int n_in,
                              void* d_out, int out_size, void* d_ws, size_t ws_size,
                              hipStream_t stream)
{
    const float* features  = (const float*)d_in[0];
    const float* proposals = (const float*)d_in[1];
    const float* fc1_w = (const float*)d_in[2];
    const float* fc1_b = (const float*)d_in[3];
    const float* fc2_w = (const float*)d_in[4];
    const float* fc2_b = (const float*)d_in[5];
    const float* cls_w = (const float*)d_in[6];
    const float* cls_b = (const float*)d_in[7];
    const float* bbox_w = (const float*)d_in[8];
    const float* bbox_b = (const float*)d_in[9];
    const int* img_sz = (const int*)d_in[10];
    float* out = (float*)d_out;
    char* ws = (char*)d_ws;
    _Float16* xhi   = (_Float16*)(ws + XHI_OFF);
    _Float16* xlo   = (_Float16*)(ws + XLO_OFF);
    _Float16* wt1hi = (_Float16*)(ws + WT1HI_OFF);
    _Float16* wt1lo = (_Float16*)(ws + WT1LO_OFF);
    _Float16* wt2hi = (_Float16*)(ws + WT2HI_OFF);
    _Float16* wt2lo = (_Float16*)(ws + WT2LO_OFF);
    _Float16* h1hi  = (_Float16*)(ws + H1HI_OFF);
    _Float16* h1lo  = (_Float16*)(ws + H1LO_OFF);
    float*  h2     = (float*) (ws + H2_OFF);
    float*  cwT    = (float*) (ws + CWT_OFF);
    float*  bwT    = (float*) (ws + BWT_OFF);
    float*  probs  = (float*) (ws + PROBS_OFF);
    float*  cur    = (float*) (ws + CUR_OFF);
    int*    cnt    = (int*)   (ws + CNT_OFF);
    float*  cscore = (float*) (ws + CS_OFF);
    float4* cbox   = (float4*)(ws + CBX_OFF);
    float4* cob    = (float4*)(ws + COB_OFF);
    float*  carea  = (float*) (ws + CAR_OFF);
    int*    clabel = (int*)   (ws + CLB_OFF);
    int*    coidx  = (int*)   (ws + CIX_OFF);
    float*  part   = (float*) (ws + PART_OFF);

    init_kernel<<<1, 64, 0, stream>>>(cnt);
    hipMemcpyAsync(cur, proposals, (size_t)NROWS*4*sizeof(float),
                   hipMemcpyDeviceToDevice, stream);
    // head-weight transposes (all stages, once)
    trans_naive<<<(3*NCLS*HID + 255)/256, 256, 0, stream>>>(cls_w, cwT, HID, NCLS, 3);
    trans_naive<<<(3*4*HID + 255)/256, 256, 0, stream>>>(bbox_w, bwT, HID, 4, 3);

    for (int st = 0; st < 3; ++st) {
        roi_align_kernel<<<NROWS, 256, 0, stream>>>(features, cur, xhi, xlo);
        // fc1 weights -> transposed f16 limbs [N][K]
        trans_limb<<<dim3(HID/32, INDIM/32), 256, 0, stream>>>(
            fc1_w + (size_t)st*INDIM*HID, wt1hi, wt1lo, INDIM, HID, 64.0f);
        // fc1: K=12544, split-K 14 x 28 steps
        mfma_gemm_limb<<<dim3(8, 8, 14), 256, 0, stream>>>(
            xhi, xlo, wt1hi, wt1lo, part, INDIM, 28);
        reduce_bias_relu<<<(NROWS*HID)/256, 256, 0, stream>>>(
            part, fc1_b + st*HID, nullptr, h1hi, h1lo, 14, 1);
        // fc2 weights
        trans_limb<<<dim3(HID/32, HID/32), 256, 0, stream>>>(
            fc2_w + (size_t)st*HID*HID, wt2hi, wt2lo, HID, HID, 64.0f);
        // fc2: K=1024, split-K 8 x 4 steps
        mfma_gemm_limb<<<dim3(8, 8, 8), 256, 0, stream>>>(
            h1hi, h1lo, wt2hi, wt2lo, part, HID, 4);
        reduce_bias_relu<<<(NROWS*HID)/256, 256, 0, stream>>>(
            part, fc2_b + st*HID, h2, nullptr, nullptr, 8, 0);
        heads_kernel<<<NROWS/4, 512, 0, stream>>>(
            h2, cwT + (size_t)st*NCLS*HID, cls_b + st*NCLS,
            bwT + (size_t)st*4*HID, bbox_b + st*4,
            cur, probs, img_sz, st, st == 2 ? 1 : 0);
    }
    compact_kernel<<<(NB*CAND_PER_IMG)/256, 256, 0, stream>>>(
        probs, cur, img_sz, cnt, cscore, cbox, cob, carea, clabel, coidx);
    nms_kernel<<<NB, 256, 0, stream>>>(
        cnt, cscore, cbox, cob, carea, clabel, coidx, out);
}